// Round 1
// baseline (1200.802 us; speedup 1.0000x reference)
//
#include <hip/hip_runtime.h>

#define N_NODES 100000
#define N_EDGES 1600000
#define N_GRAPHS_C 64
#define IN_F 86
#define H 64

// ---------------- k1: BN stats (per-feature sum & sumsq) ----------------
__global__ void bn_stats_k(const float* __restrict__ x,
                           float* __restrict__ bnsum, float* __restrict__ bnsq) {
    __shared__ float ssum[IN_F];
    __shared__ float ssq[IN_F];
    for (int i = threadIdx.x; i < IN_F; i += blockDim.x) { ssum[i] = 0.f; ssq[i] = 0.f; }
    __syncthreads();
    const int total = N_NODES * IN_F;
    for (int idx = blockIdx.x * blockDim.x + threadIdx.x; idx < total;
         idx += gridDim.x * blockDim.x) {
        float v = x[idx];
        int f = idx % IN_F;
        atomicAdd(&ssum[f], v);
        atomicAdd(&ssq[f], v * v);
    }
    __syncthreads();
    for (int i = threadIdx.x; i < IN_F; i += blockDim.x) {
        atomicAdd(&bnsum[i], ssum[i]);
        atomicAdd(&bnsq[i], ssq[i]);
    }
}

// ---------------- k2: fold BN into W1 -> W1p, c1 ----------------
__global__ void prep_k(const float* __restrict__ bnsum, const float* __restrict__ bnsq,
                       const float* __restrict__ gamma, const float* __restrict__ beta,
                       const float* __restrict__ W1, const float* __restrict__ b1,
                       float* __restrict__ W1p, float* __restrict__ c1) {
    __shared__ float scale[IN_F], shift[IN_F];
    int t = threadIdx.x;
    if (t < IN_F) {
        float mean = bnsum[t] * (1.0f / N_NODES);
        float var  = bnsq[t] * (1.0f / N_NODES) - mean * mean;
        float sc = gamma[t] * rsqrtf(var + 1e-5f);
        scale[t] = sc;
        shift[t] = beta[t] - mean * sc;
    }
    __syncthreads();
    for (int idx = t; idx < IN_F * H; idx += blockDim.x) {
        int i = idx / H;
        W1p[idx] = scale[i] * W1[idx];
    }
    if (t < H) {
        float acc = b1[t];
        for (int i = 0; i < IN_F; i++) acc += shift[i] * W1[i * H + t];
        c1[t] = acc;
    }
}

// ---------------- k3: Y[N,64] = X[N,K] @ W[K,64] + bias ----------------
// blockDim = ROWS*64
template <int ROWS, int KMAX>
__global__ void gemm_k(const float* __restrict__ X, const float* __restrict__ W,
                       const float* __restrict__ bias, float* __restrict__ Y,
                       int N, int K) {
    __shared__ float Wl[KMAX * H];
    __shared__ float Xl[ROWS][KMAX + 2];
    int tid = threadIdx.x;
    for (int i = tid; i < K * H; i += blockDim.x) Wl[i] = W[i];
    int row0 = blockIdx.x * ROWS;
    for (int i = tid; i < ROWS * K; i += blockDim.x) {
        int r = i / K, k = i % K;
        int gr = row0 + r;
        Xl[r][k] = (gr < N) ? X[gr * K + k] : 0.f;
    }
    __syncthreads();
    int col = tid & 63;
    int r = tid >> 6;
    int gr = row0 + r;
    if (gr < N) {
        float acc = bias[col];
        for (int k = 0; k < K; k++) acc += Xl[r][k] * Wl[k * H + col];
        Y[gr * H + col] = acc;
    }
}

// ---------------- k4: in-degree count ----------------
__global__ void degree_k(const int* __restrict__ dst, int* __restrict__ deg) {
    int t = blockIdx.x * blockDim.x + threadIdx.x;
    if (t < N_EDGES) atomicAdd(&deg[dst[t]], 1);
}

// ---------------- k5: edge scatter-add (wave per edge, lane = feature) ----------------
__global__ void scatter_k(const float* __restrict__ g, const int* __restrict__ src,
                          const int* __restrict__ dst, float* __restrict__ agg) {
    int lane = threadIdx.x & 63;
    int wid = blockIdx.x * (blockDim.x >> 6) + (threadIdx.x >> 6);
    int nw = gridDim.x * (blockDim.x >> 6);
    for (int e = wid; e < N_EDGES; e += nw) {
        int s = src[e];
        int d = dst[e];
        atomicAdd(&agg[d * H + lane], g[s * H + lane]);
    }
}

// ---------------- k6: mean + deg0 fallback + ReLU (in-place on agg) ----------------
__global__ void finalize_k(float* __restrict__ agg, const float* __restrict__ g,
                           const int* __restrict__ deg) {
    int t = blockIdx.x * blockDim.x + threadIdx.x;
    const int total = N_NODES * H;
    if (t >= total) return;
    int v = t >> 6;
    float a = agg[t];
    int d = deg[v];
    float val = (d > 0) ? a / (float)d : g[t];
    agg[t] = fmaxf(val, 0.f);
}

// ---------------- k7: per-graph pooled sums (graph_ids sorted -> run-length) ----------------
__global__ void pool_k(const float* __restrict__ h, const int* __restrict__ gid,
                       float* __restrict__ gsum, int* __restrict__ gcnt) {
    int lane = threadIdx.x & 63;
    int wpb = blockDim.x >> 6;
    int gw = blockIdx.x * wpb + (threadIdx.x >> 6);
    int nw = gridDim.x * wpb;
    int chunk = (N_NODES + nw - 1) / nw;
    int n0 = gw * chunk;
    int n1 = min(n0 + chunk, N_NODES);
    float acc = 0.f;
    int cur = -1, cnt = 0;
    for (int n = n0; n < n1; n++) {
        int g = gid[n];
        if (g != cur) {
            if (cur >= 0) {
                atomicAdd(&gsum[cur * H + lane], acc);
                if (lane == 0) atomicAdd(&gcnt[cur], cnt);
            }
            cur = g; acc = 0.f; cnt = 0;
        }
        acc += h[n * H + lane];
        cnt++;
    }
    if (cur >= 0) {
        atomicAdd(&gsum[cur * H + lane], acc);
        if (lane == 0) atomicAdd(&gcnt[cur], cnt);
    }
}

// ---------------- k8: FC head + sigmoid ----------------
__global__ void head_k(const float* __restrict__ gsum, const int* __restrict__ gcnt,
                       const float* __restrict__ fc1w, const float* __restrict__ fc1b,
                       const float* __restrict__ fc2w, const float* __restrict__ fc2b,
                       float* __restrict__ out) {
    int b = threadIdx.x;
    if (b >= N_GRAPHS_C) return;
    float hg[H];
    float inv = 1.0f / fmaxf((float)gcnt[b], 1.0f);
    for (int k = 0; k < H; k++) hg[k] = gsum[b * H + k] * inv;
    float z = fc2b[0];
    for (int j = 0; j < 32; j++) {
        float t = fc1b[j];
        for (int k = 0; k < H; k++) t += hg[k] * fc1w[k * 32 + j];
        z += t * fc2w[j];
    }
    out[b] = 1.0f / (1.0f + expf(-z));
}

extern "C" void kernel_launch(void* const* d_in, const int* in_sizes, int n_in,
                              void* d_out, int out_size, void* d_ws, size_t ws_size,
                              hipStream_t stream) {
    const float* x        = (const float*)d_in[0];
    const int*   edge_src = (const int*)d_in[1];
    const int*   edge_dst = (const int*)d_in[2];
    const int*   gid      = (const int*)d_in[3];
    // d_in[4] = num_graphs (scalar, fixed 64)
    const float* bn_gamma = (const float*)d_in[5];
    const float* bn_beta  = (const float*)d_in[6];
    const float* W1       = (const float*)d_in[7];
    const float* b1       = (const float*)d_in[8];
    const float* W2       = (const float*)d_in[9];
    const float* b2       = (const float*)d_in[10];
    const float* fc1w     = (const float*)d_in[11];
    const float* fc1b     = (const float*)d_in[12];
    const float* fc2w     = (const float*)d_in[13];
    const float* fc2b     = (const float*)d_in[14];
    float* out = (float*)d_out;

    // ---- workspace layout ----
    char* ws = (char*)d_ws;
    size_t off = 0;
    auto alloc = [&](size_t bytes) { void* p = ws + off; off += (bytes + 255) & ~(size_t)255; return p; };
    float* bnsum = (float*)alloc(IN_F * sizeof(float) * 2);     // bnsum[86] + bnsq[86] contiguous
    float* bnsq  = bnsum + IN_F;
    float* W1p   = (float*)alloc(IN_F * H * sizeof(float));
    float* c1    = (float*)alloc(H * sizeof(float));
    float* gsum  = (float*)alloc(N_GRAPHS_C * H * sizeof(float) + N_GRAPHS_C * sizeof(int));
    int*   gcnt  = (int*)(gsum + N_GRAPHS_C * H);
    int*   deg   = (int*)alloc(N_NODES * sizeof(int));
    float* gbuf  = (float*)alloc((size_t)N_NODES * H * sizeof(float));
    float* agg   = (float*)alloc((size_t)N_NODES * H * sizeof(float));

    // ---- zero the accumulators (ws is poisoned 0xAA each call) ----
    hipMemsetAsync(bnsum, 0, IN_F * sizeof(float) * 2, stream);
    hipMemsetAsync(deg, 0, N_NODES * sizeof(int), stream);

    // 1. BN stats
    bn_stats_k<<<512, 256, 0, stream>>>(x, bnsum, bnsq);
    // 2. fold BN into W1
    prep_k<<<1, 256, 0, stream>>>(bnsum, bnsq, bn_gamma, bn_beta, W1, b1, W1p, c1);
    // 3. g1 = x @ W1p + c1   [N,86]@[86,64]
    gemm_k<8, 96><<<(N_NODES + 7) / 8, 512, 0, stream>>>(x, W1p, c1, gbuf, N_NODES, IN_F);
    // 4. degrees
    degree_k<<<(N_EDGES + 255) / 256, 256, 0, stream>>>(edge_dst, deg);
    // 5. layer-1 aggregation
    hipMemsetAsync(agg, 0, (size_t)N_NODES * H * sizeof(float), stream);
    scatter_k<<<16384, 256, 0, stream>>>(gbuf, edge_src, edge_dst, agg);
    finalize_k<<<(N_NODES * H + 255) / 256, 256, 0, stream>>>(agg, gbuf, deg);  // h1 in agg
    // 6. g2 = h1 @ W2 + b2   [N,64]@[64,64]
    gemm_k<8, 64><<<(N_NODES + 7) / 8, 512, 0, stream>>>(agg, W2, b2, gbuf, N_NODES, H);
    // 7. layer-2 aggregation
    hipMemsetAsync(agg, 0, (size_t)N_NODES * H * sizeof(float), stream);
    scatter_k<<<16384, 256, 0, stream>>>(gbuf, edge_src, edge_dst, agg);
    finalize_k<<<(N_NODES * H + 255) / 256, 256, 0, stream>>>(agg, gbuf, deg);  // h2 in agg
    // 8. per-graph mean pool
    hipMemsetAsync(gsum, 0, N_GRAPHS_C * H * sizeof(float) + N_GRAPHS_C * sizeof(int), stream);
    pool_k<<<256, 256, 0, stream>>>(agg, gid, gsum, gcnt);
    // 9. FC head
    head_k<<<1, 64, 0, stream>>>(gsum, gcnt, fc1w, fc1b, fc2w, fc2b, out);
}

// Round 2
// 621.518 us; speedup vs baseline: 1.9320x; 1.9320x over previous
//
#include <hip/hip_runtime.h>

#define N_NODES 100000
#define N_EDGES 1600000
#define N_GRAPHS_C 64
#define IN_F 86
#define H 64
#define NB_SCAN 98  // ceil(100000/1024)

// ---------------- k1: BN stats (per-feature sum & sumsq) ----------------
__global__ void bn_stats_k(const float* __restrict__ x,
                           float* __restrict__ bnsum, float* __restrict__ bnsq) {
    __shared__ float ssum[IN_F];
    __shared__ float ssq[IN_F];
    for (int i = threadIdx.x; i < IN_F; i += blockDim.x) { ssum[i] = 0.f; ssq[i] = 0.f; }
    __syncthreads();
    const int total = N_NODES * IN_F;
    for (int idx = blockIdx.x * blockDim.x + threadIdx.x; idx < total;
         idx += gridDim.x * blockDim.x) {
        float v = x[idx];
        int f = idx % IN_F;
        atomicAdd(&ssum[f], v);
        atomicAdd(&ssq[f], v * v);
    }
    __syncthreads();
    for (int i = threadIdx.x; i < IN_F; i += blockDim.x) {
        atomicAdd(&bnsum[i], ssum[i]);
        atomicAdd(&bnsq[i], ssq[i]);
    }
}

// ---------------- k2: fold BN into W1 -> W1p, c1 ----------------
__global__ void prep_k(const float* __restrict__ bnsum, const float* __restrict__ bnsq,
                       const float* __restrict__ gamma, const float* __restrict__ beta,
                       const float* __restrict__ W1, const float* __restrict__ b1,
                       float* __restrict__ W1p, float* __restrict__ c1) {
    __shared__ float scale[IN_F], shift[IN_F];
    int t = threadIdx.x;
    if (t < IN_F) {
        float mean = bnsum[t] * (1.0f / N_NODES);
        float var  = bnsq[t] * (1.0f / N_NODES) - mean * mean;
        float sc = gamma[t] * rsqrtf(var + 1e-5f);
        scale[t] = sc;
        shift[t] = beta[t] - mean * sc;
    }
    __syncthreads();
    for (int idx = t; idx < IN_F * H; idx += blockDim.x) {
        int i = idx / H;
        W1p[idx] = scale[i] * W1[idx];
    }
    if (t < H) {
        float acc = b1[t];
        for (int i = 0; i < IN_F; i++) acc += shift[i] * W1[i * H + t];
        c1[t] = acc;
    }
}

// ---------------- degree count ----------------
__global__ void degree_k(const int* __restrict__ dst, int* __restrict__ deg) {
    int t = blockIdx.x * blockDim.x + threadIdx.x;
    if (t < N_EDGES) atomicAdd(&deg[dst[t]], 1);
}

// ---------------- scan (3-kernel exclusive prefix over 100K ints) ----------------
__global__ void scan_blocks_k(const int* __restrict__ deg, int* __restrict__ rs,
                              int* __restrict__ partials) {
    __shared__ int tmp[1024];
    int t = threadIdx.x;
    int gi = blockIdx.x * 1024 + t;
    int v = (gi < N_NODES) ? deg[gi] : 0;
    tmp[t] = v;
    __syncthreads();
    for (int off = 1; off < 1024; off <<= 1) {
        int a = (t >= off) ? tmp[t - off] : 0;
        __syncthreads();
        tmp[t] += a;
        __syncthreads();
    }
    if (gi < N_NODES) rs[gi] = tmp[t] - v;  // exclusive
    if (t == 1023) partials[blockIdx.x] = tmp[t];
}

__global__ void scan_partials_k(int* __restrict__ partials) {
    __shared__ int tmp[128];
    int t = threadIdx.x;
    int v = (t < NB_SCAN) ? partials[t] : 0;
    tmp[t] = v;
    __syncthreads();
    for (int off = 1; off < 128; off <<= 1) {
        int a = (t >= off) ? tmp[t - off] : 0;
        __syncthreads();
        tmp[t] += a;
        __syncthreads();
    }
    if (t < NB_SCAN) partials[t] = tmp[t] - v;  // exclusive
}

__global__ void scan_add_k(int* __restrict__ rs, const int* __restrict__ partials) {
    int gi = blockIdx.x * 1024 + threadIdx.x;
    if (gi < N_NODES) rs[gi] += partials[blockIdx.x];
}

// ---------------- CSR fill: after this, rs[d] == row END of node d ----------------
__global__ void fill_k(const int* __restrict__ src, const int* __restrict__ dst,
                       int* __restrict__ rs, int* __restrict__ csr) {
    int e = blockIdx.x * blockDim.x + threadIdx.x;
    if (e < N_EDGES) {
        int d = dst[e];
        int pos = atomicAdd(&rs[d], 1);
        csr[pos] = src[e];
    }
}

// ---------------- GEMM: Y[N,64] = X[N,K] @ W[K,64] + bias ----------------
// block 256 threads -> 64-row x 64-col tile; thread = 4 rows x 4 cols.
template <int K>
__global__ __launch_bounds__(256) void gemm_t(const float* __restrict__ X,
                                              const float* __restrict__ W,
                                              const float* __restrict__ bias,
                                              float* __restrict__ Y, int N) {
    __shared__ __align__(16) float Xl[64][K + 1];
    __shared__ __align__(16) float Wl[K][64];
    int tid = threadIdx.x;
    int row0 = blockIdx.x * 64;
    for (int i = tid; i < K * 64; i += 256) Wl[i / 64][i % 64] = W[i];
    for (int i = tid; i < 64 * K; i += 256) {
        int r = i / K, c = i % K;
        Xl[r][c] = (row0 + r < N) ? X[(size_t)(row0 + r) * K + c] : 0.f;
    }
    __syncthreads();
    int cg = tid & 15, rg = tid >> 4;
    float4 b4 = *(const float4*)&bias[cg * 4];
    float acc[4][4];
    for (int i = 0; i < 4; i++) { acc[i][0] = b4.x; acc[i][1] = b4.y; acc[i][2] = b4.z; acc[i][3] = b4.w; }
    for (int k = 0; k < K; k++) {
        float4 w = *(const float4*)&Wl[k][cg * 4];
        float x0 = Xl[rg * 4 + 0][k];
        float x1 = Xl[rg * 4 + 1][k];
        float x2 = Xl[rg * 4 + 2][k];
        float x3 = Xl[rg * 4 + 3][k];
        acc[0][0] += x0 * w.x; acc[0][1] += x0 * w.y; acc[0][2] += x0 * w.z; acc[0][3] += x0 * w.w;
        acc[1][0] += x1 * w.x; acc[1][1] += x1 * w.y; acc[1][2] += x1 * w.z; acc[1][3] += x1 * w.w;
        acc[2][0] += x2 * w.x; acc[2][1] += x2 * w.y; acc[2][2] += x2 * w.z; acc[2][3] += x2 * w.w;
        acc[3][0] += x3 * w.x; acc[3][1] += x3 * w.y; acc[3][2] += x3 * w.z; acc[3][3] += x3 * w.w;
    }
    for (int i = 0; i < 4; i++) {
        int gr = row0 + rg * 4 + i;
        if (gr < N) {
            float4 o = make_float4(acc[i][0], acc[i][1], acc[i][2], acc[i][3]);
            *(float4*)&Y[(size_t)gr * 64 + cg * 4] = o;
        }
    }
}

// ---------------- gather: h[n] = relu(mean of in-neighbors' g, or g[n] if deg==0) ----------------
// one wave per node, lane = feature. rs is POST-fill (rs[n] = row end).
__global__ void gather_k(const float* __restrict__ g, const int* __restrict__ rs,
                         const int* __restrict__ csr, float* __restrict__ out) {
    int lane = threadIdx.x & 63;
    int n = blockIdx.x * (blockDim.x >> 6) + (threadIdx.x >> 6);
    if (n >= N_NODES) return;
    int start = (n == 0) ? 0 : rs[n - 1];
    int end = rs[n];
    float a0 = 0.f, a1 = 0.f, a2 = 0.f, a3 = 0.f;
    for (int j0 = start; j0 < end; j0 += 64) {
        int cnt = min(64, end - j0);
        int myidx = (lane < cnt) ? csr[j0 + lane] : 0;
        int j = 0;
        for (; j + 3 < cnt; j += 4) {
            int s0 = __shfl(myidx, j, 64);
            int s1 = __shfl(myidx, j + 1, 64);
            int s2 = __shfl(myidx, j + 2, 64);
            int s3 = __shfl(myidx, j + 3, 64);
            a0 += g[(size_t)s0 * H + lane];
            a1 += g[(size_t)s1 * H + lane];
            a2 += g[(size_t)s2 * H + lane];
            a3 += g[(size_t)s3 * H + lane];
        }
        for (; j < cnt; j++) {
            int s = __shfl(myidx, j, 64);
            a0 += g[(size_t)s * H + lane];
        }
    }
    int d = end - start;
    float acc = (a0 + a1) + (a2 + a3);
    float val = (d > 0) ? acc / (float)d : g[(size_t)n * H + lane];
    out[(size_t)n * H + lane] = fmaxf(val, 0.f);
}

// ---------------- per-graph pooled sums (graph_ids sorted -> run-length) ----------------
__global__ void pool_k(const float* __restrict__ h, const int* __restrict__ gid,
                       float* __restrict__ gsum, int* __restrict__ gcnt) {
    int lane = threadIdx.x & 63;
    int wpb = blockDim.x >> 6;
    int gw = blockIdx.x * wpb + (threadIdx.x >> 6);
    int nw = gridDim.x * wpb;
    int chunk = (N_NODES + nw - 1) / nw;
    int n0 = gw * chunk;
    int n1 = min(n0 + chunk, N_NODES);
    float acc = 0.f;
    int cur = -1, cnt = 0;
    for (int n = n0; n < n1; n++) {
        int g = gid[n];
        if (g != cur) {
            if (cur >= 0) {
                atomicAdd(&gsum[cur * H + lane], acc);
                if (lane == 0) atomicAdd(&gcnt[cur], cnt);
            }
            cur = g; acc = 0.f; cnt = 0;
        }
        acc += h[(size_t)n * H + lane];
        cnt++;
    }
    if (cur >= 0) {
        atomicAdd(&gsum[cur * H + lane], acc);
        if (lane == 0) atomicAdd(&gcnt[cur], cnt);
    }
}

// ---------------- FC head + sigmoid ----------------
__global__ void head_k(const float* __restrict__ gsum, const int* __restrict__ gcnt,
                       const float* __restrict__ fc1w, const float* __restrict__ fc1b,
                       const float* __restrict__ fc2w, const float* __restrict__ fc2b,
                       float* __restrict__ out) {
    int b = threadIdx.x;
    if (b >= N_GRAPHS_C) return;
    float hg[H];
    float inv = 1.0f / fmaxf((float)gcnt[b], 1.0f);
    for (int k = 0; k < H; k++) hg[k] = gsum[b * H + k] * inv;
    float z = fc2b[0];
    for (int j = 0; j < 32; j++) {
        float t = fc1b[j];
        for (int k = 0; k < H; k++) t += hg[k] * fc1w[k * 32 + j];
        z += t * fc2w[j];
    }
    out[b] = 1.0f / (1.0f + expf(-z));
}

extern "C" void kernel_launch(void* const* d_in, const int* in_sizes, int n_in,
                              void* d_out, int out_size, void* d_ws, size_t ws_size,
                              hipStream_t stream) {
    const float* x        = (const float*)d_in[0];
    const int*   edge_src = (const int*)d_in[1];
    const int*   edge_dst = (const int*)d_in[2];
    const int*   gid      = (const int*)d_in[3];
    const float* bn_gamma = (const float*)d_in[5];
    const float* bn_beta  = (const float*)d_in[6];
    const float* W1       = (const float*)d_in[7];
    const float* b1       = (const float*)d_in[8];
    const float* W2       = (const float*)d_in[9];
    const float* b2       = (const float*)d_in[10];
    const float* fc1w     = (const float*)d_in[11];
    const float* fc1b     = (const float*)d_in[12];
    const float* fc2w     = (const float*)d_in[13];
    const float* fc2b     = (const float*)d_in[14];
    float* out = (float*)d_out;

    // ---- workspace layout ----
    char* ws = (char*)d_ws;
    size_t off = 0;
    auto alloc = [&](size_t bytes) { void* p = ws + off; off += (bytes + 255) & ~(size_t)255; return p; };
    float* bnsum    = (float*)alloc(IN_F * sizeof(float) * 2);
    float* bnsq     = bnsum + IN_F;
    float* W1p      = (float*)alloc(IN_F * H * sizeof(float));
    float* c1       = (float*)alloc(H * sizeof(float));
    float* gsum     = (float*)alloc(N_GRAPHS_C * H * sizeof(float) + N_GRAPHS_C * sizeof(int));
    int*   gcnt     = (int*)(gsum + N_GRAPHS_C * H);
    int*   deg      = (int*)alloc(N_NODES * sizeof(int));
    int*   rs       = (int*)alloc(N_NODES * sizeof(int));
    int*   partials = (int*)alloc(128 * sizeof(int));
    int*   csr      = (int*)alloc((size_t)N_EDGES * sizeof(int));
    float* gbuf     = (float*)alloc((size_t)N_NODES * H * sizeof(float));
    float* agg      = (float*)alloc((size_t)N_NODES * H * sizeof(float));

    hipMemsetAsync(bnsum, 0, IN_F * sizeof(float) * 2, stream);
    hipMemsetAsync(deg, 0, N_NODES * sizeof(int), stream);
    hipMemsetAsync(gsum, 0, N_GRAPHS_C * H * sizeof(float) + N_GRAPHS_C * sizeof(int), stream);

    // ---- CSR build (used by both layers) ----
    degree_k<<<(N_EDGES + 255) / 256, 256, 0, stream>>>(edge_dst, deg);
    scan_blocks_k<<<NB_SCAN, 1024, 0, stream>>>(deg, rs, partials);
    scan_partials_k<<<1, 128, 0, stream>>>(partials);
    scan_add_k<<<NB_SCAN, 1024, 0, stream>>>(rs, partials);
    fill_k<<<(N_EDGES + 255) / 256, 256, 0, stream>>>(edge_src, edge_dst, rs, csr);

    // ---- BN fold ----
    bn_stats_k<<<512, 256, 0, stream>>>(x, bnsum, bnsq);
    prep_k<<<1, 256, 0, stream>>>(bnsum, bnsq, bn_gamma, bn_beta, W1, b1, W1p, c1);

    // ---- layer 1: g1 = x @ W1p + c1 ; h1 = relu(mean-agg(g1)) ----
    gemm_t<IN_F><<<(N_NODES + 63) / 64, 256, 0, stream>>>(x, W1p, c1, gbuf, N_NODES);
    gather_k<<<(N_NODES + 3) / 4, 256, 0, stream>>>(gbuf, rs, csr, agg);

    // ---- layer 2: g2 = h1 @ W2 + b2 ; h2 = relu(mean-agg(g2)) ----
    gemm_t<H><<<(N_NODES + 63) / 64, 256, 0, stream>>>(agg, W2, b2, gbuf, N_NODES);
    gather_k<<<(N_NODES + 3) / 4, 256, 0, stream>>>(gbuf, rs, csr, agg);

    // ---- pool + head ----
    pool_k<<<256, 256, 0, stream>>>(agg, gid, gsum, gcnt);
    head_k<<<1, 64, 0, stream>>>(gsum, gcnt, fc1w, fc1b, fc2w, fc2b, out);
}

// Round 3
// 447.908 us; speedup vs baseline: 2.6809x; 1.3876x over previous
//
#include <hip/hip_runtime.h>

#define N_NODES 100000
#define N_EDGES 1600000
#define N_GRAPHS_C 64
#define IN_F 86
#define H 64
#define N_BKT 391            // ceil(100000/256), bucket = dst >> 8
#define SC_EPT 8             // edges per thread in bucket passes
#define SC_TILE 2048         // 256 threads * 8
#define SC_GRID 782          // ceil(1.6M / 2048)

// ---------------- BN stats: stride-invariant feature index ----------------
// grid 430 x 256 = 110080 threads; 110080 % 86 == 0 -> f = idx % 86 is
// constant per thread -> register accumulation, coalesced loads.
__global__ void bn_stats_k(const float* __restrict__ x,
                           float* __restrict__ bnsum, float* __restrict__ bnsq) {
    __shared__ float s1[IN_F], s2[IN_F];
    int tid = threadIdx.x;
    if (tid < IN_F) { s1[tid] = 0.f; s2[tid] = 0.f; }
    __syncthreads();
    const int T = 430 * 256;
    int t = blockIdx.x * 256 + tid;
    float sum = 0.f, sq = 0.f;
    for (int idx = t; idx < N_NODES * IN_F; idx += T) {
        float v = x[idx];
        sum += v; sq += v * v;
    }
    int f = t % IN_F;
    atomicAdd(&s1[f], sum);
    atomicAdd(&s2[f], sq);
    __syncthreads();
    if (tid < IN_F) {
        atomicAdd(&bnsum[tid], s1[tid]);
        atomicAdd(&bnsq[tid], s2[tid]);
    }
}

// ---------------- fold BN into W1 -> W1p, c1 ----------------
__global__ void prep_k(const float* __restrict__ bnsum, const float* __restrict__ bnsq,
                       const float* __restrict__ gamma, const float* __restrict__ beta,
                       const float* __restrict__ W1, const float* __restrict__ b1,
                       float* __restrict__ W1p, float* __restrict__ c1) {
    __shared__ float scale[IN_F], shift[IN_F];
    int t = threadIdx.x;
    if (t < IN_F) {
        float mean = bnsum[t] * (1.0f / N_NODES);
        float var  = bnsq[t] * (1.0f / N_NODES) - mean * mean;
        float sc = gamma[t] * rsqrtf(var + 1e-5f);
        scale[t] = sc;
        shift[t] = beta[t] - mean * sc;
    }
    __syncthreads();
    for (int idx = t; idx < IN_F * H; idx += blockDim.x) {
        int i = idx / H;
        W1p[idx] = scale[i] * W1[idx];
    }
    if (t < H) {
        float acc = b1[t];
        for (int i = 0; i < IN_F; i++) acc += shift[i] * W1[i * H + t];
        c1[t] = acc;
    }
}

// ---------------- CSR pass 0: per-bucket edge counts ----------------
__global__ void bucket_count_k(const int* __restrict__ dst, int* __restrict__ bcnt) {
    __shared__ int hist[N_BKT];
    int tid = threadIdx.x;
    for (int i = tid; i < N_BKT; i += 256) hist[i] = 0;
    __syncthreads();
    int e0 = blockIdx.x * SC_TILE;
#pragma unroll
    for (int i = 0; i < SC_EPT; i++) {
        int e = e0 + i * 256 + tid;
        if (e < N_EDGES) atomicAdd(&hist[dst[e] >> 8], 1);
    }
    __syncthreads();
    for (int i = tid; i < N_BKT; i += 256) atomicAdd(&bcnt[i], hist[i]);
}

// ---------------- CSR scan: bucket starts (excl) -> bstart[392], gcursor ----------------
__global__ void bucket_scan_k(const int* __restrict__ bcnt, int* __restrict__ bstart,
                              int* __restrict__ gcursor) {
    __shared__ int tmp[512];
    int t = threadIdx.x;
    int v = (t < N_BKT) ? bcnt[t] : 0;
    tmp[t] = v;
    __syncthreads();
    for (int off = 1; off < 512; off <<= 1) {
        int a = (t >= off) ? tmp[t - off] : 0;
        __syncthreads();
        tmp[t] += a;
        __syncthreads();
    }
    if (t < N_BKT) { bstart[t] = tmp[t] - v; gcursor[t] = tmp[t] - v; }
    if (t == N_BKT - 1) bstart[N_BKT] = tmp[t];
}

// ---------------- CSR pass 1: partition edges into bucket order ----------------
__global__ void bucket_scatter_k(const int* __restrict__ src, const int* __restrict__ dst,
                                 int* __restrict__ gcursor, int2* __restrict__ ebkt) {
    __shared__ int hist[N_BKT];
    __shared__ int base[N_BKT];
    int tid = threadIdx.x;
    for (int i = tid; i < N_BKT; i += 256) hist[i] = 0;
    __syncthreads();
    int e0 = blockIdx.x * SC_TILE;
    int es[SC_EPT], ed[SC_EPT], lo[SC_EPT];
#pragma unroll
    for (int i = 0; i < SC_EPT; i++) {
        int e = e0 + i * 256 + tid;
        if (e < N_EDGES) {
            es[i] = src[e];
            ed[i] = dst[e];
            lo[i] = atomicAdd(&hist[ed[i] >> 8], 1);
        }
    }
    __syncthreads();
    for (int i = tid; i < N_BKT; i += 256) base[i] = atomicAdd(&gcursor[i], hist[i]);
    __syncthreads();
#pragma unroll
    for (int i = 0; i < SC_EPT; i++) {
        int e = e0 + i * 256 + tid;
        if (e < N_EDGES) ebkt[base[ed[i] >> 8] + lo[i]] = make_int2(es[i], ed[i]);
    }
}

// ---------------- CSR pass 2: per-bucket degree+scan+fill -> rs, csr ----------------
// rs[n] = INCLUSIVE end of node n's csr row (global coords).
__global__ void bucket_fill_k(const int2* __restrict__ ebkt, const int* __restrict__ bstart,
                              int* __restrict__ rs, int* __restrict__ csr) {
    __shared__ int deg[256];
    __shared__ int scn[256];
    __shared__ int cur[256];
    int b = blockIdx.x;
    int tid = threadIdx.x;
    int e0 = bstart[b], e1 = bstart[b + 1];
    deg[tid] = 0;
    __syncthreads();
    for (int e = e0 + tid; e < e1; e += 256) atomicAdd(&deg[ebkt[e].y & 255], 1);
    __syncthreads();
    scn[tid] = deg[tid];
    __syncthreads();
    for (int off = 1; off < 256; off <<= 1) {
        int a = (tid >= off) ? scn[tid - off] : 0;
        __syncthreads();
        scn[tid] += a;
        __syncthreads();
    }
    int node = (b << 8) + tid;
    if (node < N_NODES) rs[node] = e0 + scn[tid];
    cur[tid] = e0 + scn[tid] - deg[tid];
    __syncthreads();
    for (int e = e0 + tid; e < e1; e += 256) {
        int2 p = ebkt[e];
        int pos = atomicAdd(&cur[p.y & 255], 1);
        csr[pos] = p.x;
    }
}

// ---------------- GEMM: Y[N,64] = X[N,K] @ W[K,64] + bias ----------------
template <int K>
__global__ __launch_bounds__(256) void gemm_t(const float* __restrict__ X,
                                              const float* __restrict__ W,
                                              const float* __restrict__ bias,
                                              float* __restrict__ Y, int N) {
    __shared__ __align__(16) float Xl[64][K + 1];
    __shared__ __align__(16) float Wl[K][64];
    int tid = threadIdx.x;
    int row0 = blockIdx.x * 64;
    for (int i = tid; i < K * 64; i += 256) Wl[i / 64][i % 64] = W[i];
    for (int i = tid; i < 64 * K; i += 256) {
        int r = i / K, c = i % K;
        Xl[r][c] = (row0 + r < N) ? X[(size_t)(row0 + r) * K + c] : 0.f;
    }
    __syncthreads();
    int cg = tid & 15, rg = tid >> 4;
    float4 b4 = *(const float4*)&bias[cg * 4];
    float acc[4][4];
    for (int i = 0; i < 4; i++) { acc[i][0] = b4.x; acc[i][1] = b4.y; acc[i][2] = b4.z; acc[i][3] = b4.w; }
    for (int k = 0; k < K; k++) {
        float4 w = *(const float4*)&Wl[k][cg * 4];
        float x0 = Xl[rg * 4 + 0][k];
        float x1 = Xl[rg * 4 + 1][k];
        float x2 = Xl[rg * 4 + 2][k];
        float x3 = Xl[rg * 4 + 3][k];
        acc[0][0] += x0 * w.x; acc[0][1] += x0 * w.y; acc[0][2] += x0 * w.z; acc[0][3] += x0 * w.w;
        acc[1][0] += x1 * w.x; acc[1][1] += x1 * w.y; acc[1][2] += x1 * w.z; acc[1][3] += x1 * w.w;
        acc[2][0] += x2 * w.x; acc[2][1] += x2 * w.y; acc[2][2] += x2 * w.z; acc[2][3] += x2 * w.w;
        acc[3][0] += x3 * w.x; acc[3][1] += x3 * w.y; acc[3][2] += x3 * w.z; acc[3][3] += x3 * w.w;
    }
    for (int i = 0; i < 4; i++) {
        int gr = row0 + rg * 4 + i;
        if (gr < N) {
            float4 o = make_float4(acc[i][0], acc[i][1], acc[i][2], acc[i][3]);
            *(float4*)&Y[(size_t)gr * 64 + cg * 4] = o;
        }
    }
}

// ---------------- gather: h[n] = relu(mean of in-neighbors' g, or g[n]) ----------------
__global__ void gather_k(const float* __restrict__ g, const int* __restrict__ rs,
                         const int* __restrict__ csr, float* __restrict__ out) {
    int lane = threadIdx.x & 63;
    int n = blockIdx.x * (blockDim.x >> 6) + (threadIdx.x >> 6);
    if (n >= N_NODES) return;
    int start = (n == 0) ? 0 : rs[n - 1];
    int end = rs[n];
    float a0 = 0.f, a1 = 0.f, a2 = 0.f, a3 = 0.f;
    for (int j0 = start; j0 < end; j0 += 64) {
        int cnt = min(64, end - j0);
        int myidx = (lane < cnt) ? csr[j0 + lane] : 0;
        int j = 0;
        for (; j + 3 < cnt; j += 4) {
            int s0 = __shfl(myidx, j, 64);
            int s1 = __shfl(myidx, j + 1, 64);
            int s2 = __shfl(myidx, j + 2, 64);
            int s3 = __shfl(myidx, j + 3, 64);
            a0 += g[(size_t)s0 * H + lane];
            a1 += g[(size_t)s1 * H + lane];
            a2 += g[(size_t)s2 * H + lane];
            a3 += g[(size_t)s3 * H + lane];
        }
        for (; j < cnt; j++) {
            int s = __shfl(myidx, j, 64);
            a0 += g[(size_t)s * H + lane];
        }
    }
    int d = end - start;
    float acc = (a0 + a1) + (a2 + a3);
    float val = (d > 0) ? acc / (float)d : g[(size_t)n * H + lane];
    out[(size_t)n * H + lane] = fmaxf(val, 0.f);
}

// ---------------- per-graph pooled sums (graph_ids sorted -> run-length) ----------------
__global__ void pool_k(const float* __restrict__ h, const int* __restrict__ gid,
                       float* __restrict__ gsum, int* __restrict__ gcnt) {
    int lane = threadIdx.x & 63;
    int wpb = blockDim.x >> 6;
    int gw = blockIdx.x * wpb + (threadIdx.x >> 6);
    int nw = gridDim.x * wpb;
    int chunk = (N_NODES + nw - 1) / nw;
    int n0 = gw * chunk;
    int n1 = min(n0 + chunk, N_NODES);
    float acc = 0.f;
    int cur = -1, cnt = 0;
    for (int n = n0; n < n1; n++) {
        int g = gid[n];
        if (g != cur) {
            if (cur >= 0) {
                atomicAdd(&gsum[cur * H + lane], acc);
                if (lane == 0) atomicAdd(&gcnt[cur], cnt);
            }
            cur = g; acc = 0.f; cnt = 0;
        }
        acc += h[(size_t)n * H + lane];
        cnt++;
    }
    if (cur >= 0) {
        atomicAdd(&gsum[cur * H + lane], acc);
        if (lane == 0) atomicAdd(&gcnt[cur], cnt);
    }
}

// ---------------- FC head + sigmoid ----------------
__global__ void head_k(const float* __restrict__ gsum, const int* __restrict__ gcnt,
                       const float* __restrict__ fc1w, const float* __restrict__ fc1b,
                       const float* __restrict__ fc2w, const float* __restrict__ fc2b,
                       float* __restrict__ out) {
    int b = threadIdx.x;
    if (b >= N_GRAPHS_C) return;
    float hg[H];
    float inv = 1.0f / fmaxf((float)gcnt[b], 1.0f);
    for (int k = 0; k < H; k++) hg[k] = gsum[b * H + k] * inv;
    float z = fc2b[0];
    for (int j = 0; j < 32; j++) {
        float t = fc1b[j];
        for (int k = 0; k < H; k++) t += hg[k] * fc1w[k * 32 + j];
        z += t * fc2w[j];
    }
    out[b] = 1.0f / (1.0f + expf(-z));
}

extern "C" void kernel_launch(void* const* d_in, const int* in_sizes, int n_in,
                              void* d_out, int out_size, void* d_ws, size_t ws_size,
                              hipStream_t stream) {
    const float* x        = (const float*)d_in[0];
    const int*   edge_src = (const int*)d_in[1];
    const int*   edge_dst = (const int*)d_in[2];
    const int*   gid      = (const int*)d_in[3];
    const float* bn_gamma = (const float*)d_in[5];
    const float* bn_beta  = (const float*)d_in[6];
    const float* W1       = (const float*)d_in[7];
    const float* b1       = (const float*)d_in[8];
    const float* W2       = (const float*)d_in[9];
    const float* b2       = (const float*)d_in[10];
    const float* fc1w     = (const float*)d_in[11];
    const float* fc1b     = (const float*)d_in[12];
    const float* fc2w     = (const float*)d_in[13];
    const float* fc2b     = (const float*)d_in[14];
    float* out = (float*)d_out;

    // ---- workspace layout ----
    char* ws = (char*)d_ws;
    size_t off = 0;
    auto alloc = [&](size_t bytes) { void* p = ws + off; off += (bytes + 255) & ~(size_t)255; return p; };
    float* bnsum    = (float*)alloc(IN_F * sizeof(float) * 2);
    float* bnsq     = bnsum + IN_F;
    float* W1p      = (float*)alloc(IN_F * H * sizeof(float));
    float* c1       = (float*)alloc(H * sizeof(float));
    float* gsum     = (float*)alloc(N_GRAPHS_C * H * sizeof(float) + N_GRAPHS_C * sizeof(int));
    int*   gcnt     = (int*)(gsum + N_GRAPHS_C * H);
    int*   bcnt     = (int*)alloc(N_BKT * sizeof(int));
    int*   bstart   = (int*)alloc((N_BKT + 1) * sizeof(int));
    int*   gcursor  = (int*)alloc(N_BKT * sizeof(int));
    int*   rs       = (int*)alloc(N_NODES * sizeof(int));
    int*   csr      = (int*)alloc((size_t)N_EDGES * sizeof(int));
    float* gbuf     = (float*)alloc((size_t)N_NODES * H * sizeof(float));
    float* agg      = (float*)alloc((size_t)N_NODES * H * sizeof(float));
    // ebkt (12.8 MB) aliases gbuf (25.6 MB): consumed by bucket_fill_k BEFORE
    // gemm_t writes gbuf.
    int2* ebkt = (int2*)gbuf;

    hipMemsetAsync(bnsum, 0, IN_F * sizeof(float) * 2, stream);
    hipMemsetAsync(bcnt, 0, N_BKT * sizeof(int), stream);
    hipMemsetAsync(gsum, 0, N_GRAPHS_C * H * sizeof(float) + N_GRAPHS_C * sizeof(int), stream);

    // ---- CSR build (bucketed, used by both layers) ----
    bucket_count_k<<<SC_GRID, 256, 0, stream>>>(edge_dst, bcnt);
    bucket_scan_k<<<1, 512, 0, stream>>>(bcnt, bstart, gcursor);
    bucket_scatter_k<<<SC_GRID, 256, 0, stream>>>(edge_src, edge_dst, gcursor, ebkt);
    bucket_fill_k<<<N_BKT, 256, 0, stream>>>(ebkt, bstart, rs, csr);

    // ---- BN fold ----
    bn_stats_k<<<430, 256, 0, stream>>>(x, bnsum, bnsq);
    prep_k<<<1, 256, 0, stream>>>(bnsum, bnsq, bn_gamma, bn_beta, W1, b1, W1p, c1);

    // ---- layer 1: g1 = x @ W1p + c1 ; h1 = relu(mean-agg(g1)) ----
    gemm_t<IN_F><<<(N_NODES + 63) / 64, 256, 0, stream>>>(x, W1p, c1, gbuf, N_NODES);
    gather_k<<<(N_NODES + 3) / 4, 256, 0, stream>>>(gbuf, rs, csr, agg);

    // ---- layer 2: g2 = h1 @ W2 + b2 ; h2 = relu(mean-agg(g2)) ----
    gemm_t<H><<<(N_NODES + 63) / 64, 256, 0, stream>>>(agg, W2, b2, gbuf, N_NODES);
    gather_k<<<(N_NODES + 3) / 4, 256, 0, stream>>>(gbuf, rs, csr, agg);

    // ---- pool + head ----
    pool_k<<<256, 256, 0, stream>>>(agg, gid, gsum, gcnt);
    head_k<<<1, 64, 0, stream>>>(gsum, gcnt, fc1w, fc1b, fc2w, fc2b, out);
}